// Round 3
// baseline (489.955 us; speedup 1.0000x reference)
//
#include <hip/hip_runtime.h>
#include <hip/hip_bf16.h>

// Problem constants (from reference)
#define SCREEN_W 1280
#define SCREEN_H 720
#define TILE_L   16
#define NBW      80    // ceil(1280/16)
#define NBH      45    // ceil(720/16)
#define NUM_TILE 3600  // 80*45
#define N_POINTS 32768

// native clang vector type — required by __builtin_nontemporal_store
typedef int v4i __attribute__((ext_vector_type(4)));

// ---------------------------------------------------------------------------
// Kernel A: per-point AABB (xmin,ymin,xmax,ymax) as int32, matching
//   jnp.clip(v, 0, lim).astype(jnp.int32)   (truncation toward zero; all >= 0)
// Stored as int4 per point in d_ws (32768 * 16 B = 512 KB).
// ---------------------------------------------------------------------------
__global__ void aabb_kernel(const float* __restrict__ pos2d,
                            const float* __restrict__ radius,
                            int4* __restrict__ aabb) {
    int t = blockIdx.x * blockDim.x + threadIdx.x;   // thread handles 4 points
    int n = t * 4;
    if (n >= N_POINTS) return;

    // pos2d is [N,2] interleaved: floats 2n .. 2n+7 for points n..n+3
    const float4* p4 = (const float4*)(pos2d + 2 * n);
    float4 p01 = p4[0];   // x0 y0 x1 y1
    float4 p23 = p4[1];   // x2 y2 x3 y3
    float4 r   = *(const float4*)(radius + n);

    float xs[4] = {p01.x, p01.z, p23.x, p23.z};
    float ys[4] = {p01.y, p01.w, p23.y, p23.w};
    float rs[4] = {r.x, r.y, r.z, r.w};

#pragma unroll
    for (int j = 0; j < 4; ++j) {
        float x = xs[j], y = ys[j], rr = rs[j];
        int xmin = (int)fminf(fmaxf(x - rr, 0.0f), (float)SCREEN_W);
        int ymin = (int)fminf(fmaxf(y - rr, 0.0f), (float)SCREEN_H);
        int xmax = (int)fminf(fmaxf(x + rr, 0.0f), (float)SCREEN_W);
        int ymax = (int)fminf(fmaxf(y + rr, 0.0f), (float)SCREEN_H);
        aabb[n + j] = make_int4(xmin, ymin, xmax, ymax);
    }
}

// ---------------------------------------------------------------------------
// Kernel B: for tile t (blockIdx.y) and point chunk (blockIdx.x), each thread
// computes the overlap mask for 4 consecutive points and writes one int4
// (harness reads the bool output as int32: 0/1).
// Output layout: out[t * N_POINTS + n]  (tile-major, matches [T, N]).
// Tile bounds: W and H are exact multiples of 16, so right/bottom need no min.
// ---------------------------------------------------------------------------
__global__ void __launch_bounds__(256)
mask_kernel(const int4* __restrict__ aabb, int* __restrict__ out) {
    int tile = blockIdx.y;
    int n = (blockIdx.x * blockDim.x + threadIdx.x) * 4;

    // xi = tile / 45, yi = tile % 45  (compiler lowers const-division to magic mul)
    int xi = tile / NBH;
    int yi = tile - xi * NBH;
    int left   = xi * TILE_L;
    int right  = left + TILE_L;    // (xi+1)*16 <= 1280 always
    int top    = yi * TILE_L;
    int bottom = top + TILE_L;     // (yi+1)*16 <= 720 always

    v4i res;
#pragma unroll
    for (int j = 0; j < 4; ++j) {
        int4 a = aabb[n + j];      // xmin, ymin, xmax, ymax
        int otl_x = max(a.x, left);
        int otl_y = max(a.y, top);
        int obr_x = min(a.z, right);
        int obr_y = min(a.w, bottom);
        res[j] = ((obr_x > otl_x) && (obr_y > otl_y)) ? 1 : 0;
    }

    v4i* dst = (v4i*)(out + (size_t)tile * N_POINTS + n);
    __builtin_nontemporal_store(res, dst);   // streaming write; never re-read
}

extern "C" void kernel_launch(void* const* d_in, const int* in_sizes, int n_in,
                              void* d_out, int out_size, void* d_ws, size_t ws_size,
                              hipStream_t stream) {
    const float* pos2d  = (const float*)d_in[0];
    const float* radius = (const float*)d_in[1];
    int* out = (int*)d_out;
    int4* aabb = (int4*)d_ws;   // 32768 * 16 B = 512 KB

    // Kernel A: 32768 points / 4 per thread = 8192 threads
    aabb_kernel<<<dim3(8192 / 256), dim3(256), 0, stream>>>(pos2d, radius, aabb);

    // Kernel B: 32768 / (256*4) = 32 chunks x 3600 tiles
    mask_kernel<<<dim3(32, NUM_TILE), dim3(256), 0, stream>>>(aabb, out);
}

// Round 4
// 446.988 us; speedup vs baseline: 1.0961x; 1.0961x over previous
//
#include <hip/hip_runtime.h>
#include <hip/hip_bf16.h>

// Problem constants (from reference)
#define SCREEN_W 1280
#define SCREEN_H 720
#define TILE_L   16
#define NBW      80    // ceil(1280/16)
#define NBH      45    // ceil(720/16)
#define NUM_TILE 3600  // 80*45
#define N_POINTS 32768

// native clang vector type — required by __builtin_nontemporal_store
typedef int v4i __attribute__((ext_vector_type(4)));

// ---------------------------------------------------------------------------
// Kernel A: per-point tile-index ranges packed into one u32:
//   ximin | ximax<<8 | yimin<<16 | yimax<<24   (half-open: ximin <= xi < ximax)
// Derivation (W,H multiples of 16, and xmax>xmin always since r>=1 => 2r>=2px):
//   overlap_x(tile xi)  <=>  xmax > 16*xi  &&  16*xi+16 > xmin
//                       <=>  (xmin>>4) <= xi < ((xmax+15)>>4)
// Pixel AABB matches jnp.clip(v,0,lim).astype(int32) (truncation; all >= 0).
// Table: 32768 * 4 B = 128 KB in d_ws.
// ---------------------------------------------------------------------------
__global__ void aabb_kernel(const float* __restrict__ pos2d,
                            const float* __restrict__ radius,
                            unsigned int* __restrict__ pk) {
    int t = blockIdx.x * blockDim.x + threadIdx.x;   // thread handles 4 points
    int n = t * 4;
    if (n >= N_POINTS) return;

    const float4* p4 = (const float4*)(pos2d + 2 * n);
    float4 p01 = p4[0];   // x0 y0 x1 y1
    float4 p23 = p4[1];   // x2 y2 x3 y3
    float4 r   = *(const float4*)(radius + n);

    float xs[4] = {p01.x, p01.z, p23.x, p23.z};
    float ys[4] = {p01.y, p01.w, p23.y, p23.w};
    float rs[4] = {r.x, r.y, r.z, r.w};

    uint4 outp;
    unsigned int* op = &outp.x;
#pragma unroll
    for (int j = 0; j < 4; ++j) {
        float x = xs[j], y = ys[j], rr = rs[j];
        int xmin = (int)fminf(fmaxf(x - rr, 0.0f), (float)SCREEN_W);
        int ymin = (int)fminf(fmaxf(y - rr, 0.0f), (float)SCREEN_H);
        int xmax = (int)fminf(fmaxf(x + rr, 0.0f), (float)SCREEN_W);
        int ymax = (int)fminf(fmaxf(y + rr, 0.0f), (float)SCREEN_H);
        unsigned int ximin = (unsigned int)(xmin >> 4);          // <= 80
        unsigned int ximax = (unsigned int)((xmax + 15) >> 4);   // <= 80
        unsigned int yimin = (unsigned int)(ymin >> 4);          // <= 45
        unsigned int yimax = (unsigned int)((ymax + 15) >> 4);   // <= 45
        op[j] = ximin | (ximax << 8) | (yimin << 16) | (yimax << 24);
    }
    *(uint4*)(pk + n) = outp;   // one dwordx4 store for 4 points
}

// ---------------------------------------------------------------------------
// Kernel B: tile t (blockIdx.y), point chunk (blockIdx.x). Each thread loads
// ONE uint4 (4 packed points), byte-unpacks, compares vs (xi,yi), writes one
// int4 (harness reads bool output as int32 0/1) with a nontemporal store.
// Output layout: out[t * N_POINTS + n]  (tile-major [T, N]).
// ---------------------------------------------------------------------------
__global__ void __launch_bounds__(256)
mask_kernel(const uint4* __restrict__ pk, int* __restrict__ out) {
    int tile = blockIdx.y;
    int t = blockIdx.x * blockDim.x + threadIdx.x;   // thread index over uint4s
    int n = t * 4;                                    // first point index

    unsigned int xi = (unsigned int)(tile / NBH);
    unsigned int yi = (unsigned int)(tile - (int)xi * NBH);

    uint4 p = pk[t];
    const unsigned int* pp = &p.x;

    v4i res;
#pragma unroll
    for (int j = 0; j < 4; ++j) {
        unsigned int w = pp[j];
        unsigned int ximin =  w        & 0xFFu;
        unsigned int ximax = (w >> 8)  & 0xFFu;
        unsigned int yimin = (w >> 16) & 0xFFu;
        unsigned int yimax =  w >> 24;
        res[j] = (xi >= ximin && xi < ximax && yi >= yimin && yi < yimax) ? 1 : 0;
    }

    v4i* dst = (v4i*)(out + (size_t)tile * N_POINTS + n);
    __builtin_nontemporal_store(res, dst);   // streaming write; never re-read
}

extern "C" void kernel_launch(void* const* d_in, const int* in_sizes, int n_in,
                              void* d_out, int out_size, void* d_ws, size_t ws_size,
                              hipStream_t stream) {
    const float* pos2d  = (const float*)d_in[0];
    const float* radius = (const float*)d_in[1];
    int* out = (int*)d_out;
    unsigned int* pk = (unsigned int*)d_ws;   // 32768 * 4 B = 128 KB

    // Kernel A: 32768 points / 4 per thread = 8192 threads
    aabb_kernel<<<dim3(8192 / 256), dim3(256), 0, stream>>>(pos2d, radius, pk);

    // Kernel B: 32768 / (256*4) = 32 chunks x 3600 tiles
    mask_kernel<<<dim3(32, NUM_TILE), dim3(256), 0, stream>>>((const uint4*)pk, out);
}